// Round 8
// baseline (27.127 us; speedup 1.0000x reference)
//
#include <hip/hip_runtime.h>
#include <hip/hip_cooperative_groups.h>

namespace cg = cooperative_groups;

#define BB 4
#define NN 512
#define HH 64
#define NODES (BB*NN)
#define TB 8             // nodes per block (fused kernel)
#define NBLK (NODES/TB)  // 256 blocks = one per CU
#define NSL 8            // j-slices (fallback pairout)
#define JCH (NN/NSL)
#define TI 4

typedef float v4f __attribute__((ext_vector_type(4)));

// ==================== FUSED COOPERATIVE KERNEL ====================
// 256 blocks x 512 thr (8 waves). Block owns TB=8 consecutive nodes.
// Phase A (enc): wave w -> node w; lane = dim; sequential-m matmuls (R1
//   numerics); h/ai/aj to wave-local LDS; aj also to global (cross-block).
// fence -> grid.sync -> fence   (release-writeback + acquire-invalidate:
//   per-XCD L2s are not coherent; grid.sync alone is not enough)
// Phase B1 (pair): wave w -> i-quad (w&1), j-range (w>>1)*128 in 2 slices;
//   R6's proven packed-v4 inner loop; partials -> LDS.
// Phase B2 (out): slice-sum then wave-per-node sequential-m output MLP.
__global__ __launch_bounds__(512, 2) void fused_kernel(
    const float* __restrict__ pos, const int* __restrict__ box_ptr,
    const float* __restrict__ enc_w1, const float* __restrict__ enc_b1,
    const float* __restrict__ enc_w2, const float* __restrict__ enc_b2,
    const float* __restrict__ msg_w1, const float* __restrict__ msg_b1,
    const float* __restrict__ msg_w2, const float* __restrict__ msg_b2,
    const float* __restrict__ upd_w1, const float* __restrict__ upd_b1,
    const float* __restrict__ upd_w2, const float* __restrict__ upd_b2,
    const float* __restrict__ dec_w1, const float* __restrict__ dec_b1,
    const float* __restrict__ dec_w2, const float* __restrict__ dec_b2,
    float* __restrict__ aj_g, float* __restrict__ out)
{
    const int w = threadIdx.x >> 6;
    const int l = threadIdx.x & 63;
    const int ig = blockIdx.x;          // 0..255
    const int b  = ig >> 6;             // 64 blocks per batch
    const int i0l = (ig & 63) * TB;     // batch-local node base
    const int node0 = b*NN + i0l;

    __shared__ float dbuf[8][256];
    __shared__ float acc_lds[8][4][HH];
    __shared__ float t_s [TB][HH];
    __shared__ float Hs  [TB][HH];
    __shared__ float ai_s[TB][HH];
    __shared__ float aj_s[TB][HH];
    __shared__ float A   [TB][HH];
    __shared__ float G   [TB][HH];
    __shared__ float P   [TB][HH];
    __shared__ float U   [TB][HH];

    // ================= phase A: encoder (wave w -> node w) =================
    {
        const int node = node0 + w;
        const float px = pos[node*2+0];
        const float py = pos[node*2+1];
        float t = fmaf(px, enc_w1[l], fmaf(py, enc_w1[HH + l], enc_b1[l]));
        t_s[w][l] = fmaxf(t, 0.f);
        __builtin_amdgcn_wave_barrier();

        float h = enc_b2[l];
        #pragma unroll
        for (int m = 0; m < HH; ++m) h = fmaf(t_s[w][m], enc_w2[m*HH + l], h);
        Hs[w][l] = h;
        __builtin_amdgcn_wave_barrier();

        float aiv = 0.f, ajv = 0.f;
        #pragma unroll
        for (int m = 0; m < HH; ++m) {
            const float hm = Hs[w][m];
            aiv = fmaf(hm, msg_w1[m*HH + l],        aiv);
            ajv = fmaf(hm, msg_w1[(HH + m)*HH + l], ajv);
        }
        ai_s[w][l] = aiv;
        aj_s[w][l] = ajv;
        aj_g[(size_t)node*HH + l] = ajv;          // the only cross-block value
    }

    __threadfence();            // release: write-back dirty L2 (aj_g)
    cg::this_grid().sync();
    __threadfence();            // acquire: invalidate stale L2 lines (readers)

    // ================= phase B1: pair =================
    {
        const int jgrp = l >> 4;
        const int kq   = l & 15;
        const int q  = w & 1;        // i-quad (nodes q*4..q*4+3)
        const int jh = w >> 1;       // j-128 range

        const float box  = (float)box_ptr[0];
        const float hbox = 0.5f * box;
        const float2* pos2 = (const float2*)pos;
        float* db = dbuf[w];

        const v4f wd4 = *(const v4f*)(msg_w1 + 2*HH*HH + 4*kq);
        const v4f b1q = *(const v4f*)(msg_b1 + 4*kq);
        v4f base4[4];
        float2 pi[4];
        #pragma unroll
        for (int ii = 0; ii < 4; ++ii) {
            base4[ii] = *(const v4f*)(&ai_s[q*4 + ii][4*kq]) + b1q;
            pi[ii] = pos2[node0 + q*4 + ii];
        }
        v4f acc[4];
        #pragma unroll
        for (int ii = 0; ii < 4; ++ii) acc[ii] = (v4f){0.f,0.f,0.f,0.f};

        #pragma unroll
        for (int sl = 0; sl < 2; ++sl) {
            const int j0 = (jh*2 + sl) * 64;
            {
                const float2 pj = pos2[b*NN + j0 + l];
                #pragma unroll
                for (int ii = 0; ii < 4; ++ii) {
                    float dx = pj.x - pi[ii].x;
                    float dy = pj.y - pi[ii].y;
                    dx -= (dx >  hbox) ? box : 0.f;
                    dx += (dx < -hbox) ? box : 0.f;
                    dy -= (dy >  hbox) ? box : 0.f;
                    dy += (dy < -hbox) ? box : 0.f;
                    db[ii*64 + (l&3)*16 + (l>>2)] = sqrtf(fmaf(dx, dx, dy*dy));
                }
            }
            __builtin_amdgcn_wave_barrier();

            #pragma unroll
            for (int t4 = 0; t4 < 4; ++t4) {
                v4f d4[4];
                #pragma unroll
                for (int ii = 0; ii < 4; ++ii)
                    d4[ii] = *(const v4f*)(db + ii*64 + jgrp*16 + 4*t4);
                #pragma unroll
                for (int u = 0; u < 4; ++u) {
                    const int jo = (t4*4 + u)*4 + jgrp;
                    const v4f a4 = *(const v4f*)(aj_g + (size_t)(b*NN + j0 + jo)*HH + 4*kq);
                    #pragma unroll
                    for (int ii = 0; ii < 4; ++ii) {
                        v4f t = __builtin_elementwise_fma((v4f)(d4[ii][u]), wd4,
                                                          a4 + base4[ii]);
                        acc[ii] += __builtin_elementwise_max(t, (v4f){0.f,0.f,0.f,0.f});
                    }
                }
            }
            __builtin_amdgcn_wave_barrier();
        }

        #pragma unroll
        for (int ii = 0; ii < 4; ++ii) {
            #pragma unroll
            for (int c = 0; c < 4; ++c) {
                float v = acc[ii][c];
                v += __shfl_xor(v, 16, 64);
                v += __shfl_xor(v, 32, 64);
                acc[ii][c] = v;
            }
        }

        // self-term (d_ii==0 exactly -> in-loop term == relu(base+aj_i))
        {
            const int ii = jgrp;
            const int il = i0l + q*4 + ii;       // batch-local index
            v4f a = acc[ii];
            if ((il >> 7) == jh) {
                const v4f ajs = *(const v4f*)(&aj_s[q*4 + ii][4*kq]);
                a -= __builtin_elementwise_max(base4[ii] + ajs, (v4f){0.f,0.f,0.f,0.f});
            }
            *(v4f*)(&acc_lds[w][ii][4*kq]) = a;
        }
    }
    __syncthreads();

    // ================= slice-sum: wave w -> node w =================
    {
        const int q = w >> 2, ii = w & 3;
        float a = 0.f;
        #pragma unroll
        for (int jh = 0; jh < 4; ++jh) a += acc_lds[jh*2 + q][ii][l];
        A[w][l] = a;
    }
    __builtin_amdgcn_wave_barrier();

    // ================= phase B2: out MLP (wave w -> node w) =================
    const float inv = 1.f / (float)(NN - 1);

    float agg = 0.f;
    #pragma unroll
    for (int m = 0; m < HH; ++m) agg = fmaf(A[w][m], msg_w2[m*HH + l], agg);
    agg = fmaf(agg, inv, msg_b2[l]);
    G[w][l] = agg;
    __builtin_amdgcn_wave_barrier();

    float p = upd_b1[l];
    #pragma unroll
    for (int m = 0; m < HH; ++m) p = fmaf(Hs[w][m], upd_w1[m*HH + l], p);
    #pragma unroll
    for (int m = 0; m < HH; ++m) p = fmaf(G[w][m], upd_w1[(HH + m)*HH + l], p);
    P[w][l] = fmaxf(p, 0.f);
    __builtin_amdgcn_wave_barrier();

    float u = upd_b2[l];
    #pragma unroll
    for (int m = 0; m < HH; ++m) u = fmaf(P[w][m], upd_w2[m*HH + l], u);
    U[w][l] = u;
    __builtin_amdgcn_wave_barrier();

    float d = dec_b1[l];
    #pragma unroll
    for (int m = 0; m < HH; ++m) d = fmaf(U[w][m], dec_w1[m*HH + l], d);
    d = fmaxf(d, 0.f);

    float f0 = d * dec_w2[2*l + 0];
    float f1 = d * dec_w2[2*l + 1];
    #pragma unroll
    for (int off = 32; off >= 1; off >>= 1) {
        f0 += __shfl_xor(f0, off, 64);
        f1 += __shfl_xor(f1, off, 64);
    }
    if (l == 0) {
        out[(size_t)(node0 + w)*2 + 0] = f0 + dec_b2[0];
        out[(size_t)(node0 + w)*2 + 1] = f1 + dec_b2[1];
    }
}

// ==================== FALLBACK: round-6 proven kernels (26.9 us) ====================
__global__ __launch_bounds__(256) void enc_kernel(
    const float* __restrict__ pos,
    const float* __restrict__ enc_w1, const float* __restrict__ enc_b1,
    const float* __restrict__ enc_w2, const float* __restrict__ enc_b2,
    const float* __restrict__ msg_w1,
    float* __restrict__ h_out, float* __restrict__ ai_out, float* __restrict__ aj_out)
{
    const int w = threadIdx.x >> 6;
    const int k = threadIdx.x & 63;
    const int node = blockIdx.x*4 + w;
    __shared__ float t_s[4][HH];
    __shared__ float h_s[4][HH];

    const float px = pos[node*2+0];
    const float py = pos[node*2+1];

    float t = fmaf(px, enc_w1[k], fmaf(py, enc_w1[HH + k], enc_b1[k]));
    t_s[w][k] = fmaxf(t, 0.f);
    __syncthreads();

    float h = enc_b2[k];
    #pragma unroll
    for (int m = 0; m < HH; ++m) h = fmaf(t_s[w][m], enc_w2[m*HH + k], h);
    h_s[w][k] = h;
    h_out[node*HH + k] = h;
    __syncthreads();

    float aiv = 0.f, ajv = 0.f;
    #pragma unroll
    for (int m = 0; m < HH; ++m) {
        const float hm = h_s[w][m];
        aiv = fmaf(hm, msg_w1[m*HH + k],        aiv);
        ajv = fmaf(hm, msg_w1[(HH + m)*HH + k], ajv);
    }
    ai_out[node*HH + k] = aiv;
    aj_out[node*HH + k] = ajv;
}

__global__ __launch_bounds__(512, 2) void pairout_kernel(
    const float* __restrict__ pos, const int* __restrict__ box_ptr,
    const float* __restrict__ msg_w1, const float* __restrict__ msg_b1,
    const float* __restrict__ ai, const float* __restrict__ aj,
    const float* __restrict__ h_in,
    const float* __restrict__ msg_w2, const float* __restrict__ msg_b2,
    const float* __restrict__ upd_w1, const float* __restrict__ upd_b1,
    const float* __restrict__ upd_w2, const float* __restrict__ upd_b2,
    const float* __restrict__ dec_w1, const float* __restrict__ dec_b1,
    const float* __restrict__ dec_w2, const float* __restrict__ dec_b2,
    float* __restrict__ out)
{
    const int w  = threadIdx.x >> 6;
    const int l  = threadIdx.x & 63;
    const int jgrp = l >> 4;
    const int kq   = l & 15;
    const int ig = blockIdx.x;
    const int b  = ig >> 7;
    const int i0 = (ig & 127) * TI;
    const int node0 = b*NN + i0;
    const int jch0  = w * JCH;

    __shared__ float dbuf[NSL][TI*64];
    __shared__ float acc_lds[NSL][TI][HH];
    __shared__ float A [TI][HH];
    __shared__ float Hs[TI][HH];
    __shared__ float G [TI][HH];
    __shared__ float P [TI][HH];
    __shared__ float U [TI][HH];
    __shared__ float D [TI][HH];

    {
        const float box  = (float)box_ptr[0];
        const float hbox = 0.5f * box;
        const float2* pos2 = (const float2*)pos;
        float* db = dbuf[w];

        const v4f wd4 = *(const v4f*)(msg_w1 + 2*HH*HH + 4*kq);
        const v4f b1  = *(const v4f*)(msg_b1 + 4*kq);
        v4f base4[TI];
        float2 pi[TI];
        #pragma unroll
        for (int ii = 0; ii < TI; ++ii) {
            base4[ii] = *(const v4f*)(ai + (size_t)(node0 + ii)*HH + 4*kq) + b1;
            pi[ii] = pos2[node0 + ii];
        }

        {
            const float2 pj = pos2[b*NN + jch0 + l];
            #pragma unroll
            for (int ii = 0; ii < TI; ++ii) {
                float dx = pj.x - pi[ii].x;
                float dy = pj.y - pi[ii].y;
                dx -= (dx >  hbox) ? box : 0.f;
                dx += (dx < -hbox) ? box : 0.f;
                dy -= (dy >  hbox) ? box : 0.f;
                dy += (dy < -hbox) ? box : 0.f;
                db[ii*64 + (l&3)*16 + (l>>2)] = sqrtf(fmaf(dx, dx, dy*dy));
            }
        }
        __builtin_amdgcn_wave_barrier();

        v4f acc[TI];
        #pragma unroll
        for (int ii = 0; ii < TI; ++ii) acc[ii] = (v4f){0.f,0.f,0.f,0.f};

        #pragma unroll
        for (int t4 = 0; t4 < 4; ++t4) {
            v4f d4[TI];
            #pragma unroll
            for (int ii = 0; ii < TI; ++ii)
                d4[ii] = *(const v4f*)(db + ii*64 + jgrp*16 + 4*t4);
            #pragma unroll
            for (int u = 0; u < 4; ++u) {
                const int jo = (t4*4 + u)*4 + jgrp;
                const v4f a4 = *(const v4f*)(aj + (size_t)(b*NN + jch0 + jo)*HH + 4*kq);
                #pragma unroll
                for (int ii = 0; ii < TI; ++ii) {
                    const float d = d4[ii][u];
                    v4f t = __builtin_elementwise_fma((v4f)(d), wd4, a4 + base4[ii]);
                    acc[ii] += __builtin_elementwise_max(t, (v4f){0.f,0.f,0.f,0.f});
                }
            }
        }

        #pragma unroll
        for (int ii = 0; ii < TI; ++ii) {
            #pragma unroll
            for (int c = 0; c < 4; ++c) {
                float v = acc[ii][c];
                v += __shfl_xor(v, 16, 64);
                v += __shfl_xor(v, 32, 64);
                acc[ii][c] = v;
            }
        }

        {
            const int ii = jgrp;
            const int i  = i0 + ii;
            v4f a = acc[ii];
            if ((i >> 6) == w) {
                const v4f ajs = *(const v4f*)(aj + (size_t)(b*NN + i)*HH + 4*kq);
                a -= __builtin_elementwise_max(base4[ii] + ajs, (v4f){0.f,0.f,0.f,0.f});
            }
            *(v4f*)(&acc_lds[w][ii][4*kq]) = a;
        }
    }
    __syncthreads();

    if (w < 4) {
        float a = 0.f;
        #pragma unroll
        for (int s = 0; s < NSL; ++s) a += acc_lds[s][w][l];
        A[w][l] = a;
    } else {
        const int nn = w - 4;
        Hs[nn][l] = h_in[(size_t)(node0 + nn)*HH + l];
    }
    __syncthreads();

    const int nn  = w & 3;
    const int o   = w >> 2;
    const int jg8 = l >> 3;
    const int kq8 = l & 7;
    const int ocol = o*32 + 4*kq8;
    const float inv = 1.f / (float)(NN - 1);

    {
        v4f q = {0.f,0.f,0.f,0.f};
        #pragma unroll
        for (int mm = 0; mm < 8; ++mm) {
            const int m = 8*mm + jg8;
            const v4f wrow = *(const v4f*)(msg_w2 + m*HH + ocol);
            q = __builtin_elementwise_fma((v4f)(A[nn][m]), wrow, q);
        }
        #pragma unroll
        for (int c = 0; c < 4; ++c) {
            float x = q[c];
            x += __shfl_xor(x, 8, 64);
            x += __shfl_xor(x, 16, 64);
            x += __shfl_xor(x, 32, 64);
            q[c] = x;
        }
        q = __builtin_elementwise_fma(q, (v4f)(inv), *(const v4f*)(msg_b2 + ocol));
        if (jg8 == 0) *(v4f*)(&G[nn][ocol]) = q;
    }
    __syncthreads();

    {
        v4f q = {0.f,0.f,0.f,0.f};
        #pragma unroll
        for (int mm = 0; mm < 8; ++mm) {
            const int m = 8*mm + jg8;
            const v4f wrow = *(const v4f*)(upd_w1 + m*HH + ocol);
            q = __builtin_elementwise_fma((v4f)(Hs[nn][m]), wrow, q);
        }
        #pragma unroll
        for (int mm = 0; mm < 8; ++mm) {
            const int m = 8*mm + jg8;
            const v4f wrow = *(const v4f*)(upd_w1 + (size_t)(HH + m)*HH + ocol);
            q = __builtin_elementwise_fma((v4f)(G[nn][m]), wrow, q);
        }
        #pragma unroll
        for (int c = 0; c < 4; ++c) {
            float x = q[c];
            x += __shfl_xor(x, 8, 64);
            x += __shfl_xor(x, 16, 64);
            x += __shfl_xor(x, 32, 64);
            q[c] = x;
        }
        q = __builtin_elementwise_max(q + *(const v4f*)(upd_b1 + ocol),
                                      (v4f){0.f,0.f,0.f,0.f});
        if (jg8 == 0) *(v4f*)(&P[nn][ocol]) = q;
    }
    __syncthreads();

    {
        v4f q = {0.f,0.f,0.f,0.f};
        #pragma unroll
        for (int mm = 0; mm < 8; ++mm) {
            const int m = 8*mm + jg8;
            const v4f wrow = *(const v4f*)(upd_w2 + m*HH + ocol);
            q = __builtin_elementwise_fma((v4f)(P[nn][m]), wrow, q);
        }
        #pragma unroll
        for (int c = 0; c < 4; ++c) {
            float x = q[c];
            x += __shfl_xor(x, 8, 64);
            x += __shfl_xor(x, 16, 64);
            x += __shfl_xor(x, 32, 64);
            q[c] = x;
        }
        q = q + *(const v4f*)(upd_b2 + ocol);
        if (jg8 == 0) *(v4f*)(&U[nn][ocol]) = q;
    }
    __syncthreads();

    {
        v4f q = {0.f,0.f,0.f,0.f};
        #pragma unroll
        for (int mm = 0; mm < 8; ++mm) {
            const int m = 8*mm + jg8;
            const v4f wrow = *(const v4f*)(dec_w1 + m*HH + ocol);
            q = __builtin_elementwise_fma((v4f)(U[nn][m]), wrow, q);
        }
        #pragma unroll
        for (int c = 0; c < 4; ++c) {
            float x = q[c];
            x += __shfl_xor(x, 8, 64);
            x += __shfl_xor(x, 16, 64);
            x += __shfl_xor(x, 32, 64);
            q[c] = x;
        }
        q = __builtin_elementwise_max(q + *(const v4f*)(dec_b1 + ocol),
                                      (v4f){0.f,0.f,0.f,0.f});
        if (jg8 == 0) *(v4f*)(&D[nn][ocol]) = q;
    }
    __syncthreads();

    if (w < 4) {
        const float d = D[w][l];
        float f0 = d * dec_w2[2*l + 0];
        float f1 = d * dec_w2[2*l + 1];
        #pragma unroll
        for (int off = 32; off >= 1; off >>= 1) {
            f0 += __shfl_xor(f0, off, 64);
            f1 += __shfl_xor(f1, off, 64);
        }
        if (l == 0) {
            out[(size_t)(node0 + w)*2 + 0] = f0 + dec_b2[0];
            out[(size_t)(node0 + w)*2 + 1] = f1 + dec_b2[1];
        }
    }
}

extern "C" void kernel_launch(void* const* d_in, const int* in_sizes, int n_in,
                              void* d_out, int out_size, void* d_ws, size_t ws_size,
                              hipStream_t stream) {
    const float* pos    = (const float*)d_in[0];
    const int*   boxp   = (const int*)  d_in[1];
    const float* enc_w1 = (const float*)d_in[2];
    const float* enc_b1 = (const float*)d_in[3];
    const float* enc_w2 = (const float*)d_in[4];
    const float* enc_b2 = (const float*)d_in[5];
    const float* msg_w1 = (const float*)d_in[6];
    const float* msg_b1 = (const float*)d_in[7];
    const float* msg_w2 = (const float*)d_in[8];
    const float* msg_b2 = (const float*)d_in[9];
    const float* upd_w1 = (const float*)d_in[10];
    const float* upd_b1 = (const float*)d_in[11];
    const float* upd_w2 = (const float*)d_in[12];
    const float* upd_b2 = (const float*)d_in[13];
    const float* dec_w1 = (const float*)d_in[14];
    const float* dec_b1 = (const float*)d_in[15];
    const float* dec_w2 = (const float*)d_in[16];
    const float* dec_b2 = (const float*)d_in[17];

    float* ws   = (float*)d_ws;
    float* h    = ws;                          // fallback use
    float* ai   = ws + (size_t)NODES*HH;       // fallback use
    float* aj_g = ws + (size_t)2*NODES*HH;     // shared by both paths
    float* outp = (float*)d_out;

    // Deterministic environment probes (capture-safe queries, no stream ops).
    int dev = 0;
    (void)hipGetDevice(&dev);
    int coop = 0;
    (void)hipDeviceGetAttribute(&coop, hipDeviceAttributeCooperativeLaunch, dev);
    int maxblk = 0;
    (void)hipOccupancyMaxActiveBlocksPerMultiprocessor(&maxblk, fused_kernel, 512, 0);

    bool done = false;
    if (coop && maxblk >= 1) {
        void* args[] = {
            (void*)&pos, (void*)&boxp,
            (void*)&enc_w1, (void*)&enc_b1, (void*)&enc_w2, (void*)&enc_b2,
            (void*)&msg_w1, (void*)&msg_b1, (void*)&msg_w2, (void*)&msg_b2,
            (void*)&upd_w1, (void*)&upd_b1, (void*)&upd_w2, (void*)&upd_b2,
            (void*)&dec_w1, (void*)&dec_b1, (void*)&dec_w2, (void*)&dec_b2,
            (void*)&aj_g, (void*)&outp
        };
        hipError_t rc = hipLaunchCooperativeKernel((const void*)fused_kernel,
                                                   dim3(NBLK), dim3(512),
                                                   args, 0, stream);
        if (rc == hipSuccess) done = true;
        else (void)hipGetLastError();   // clear error state before fallback
    }

    if (!done) {
        enc_kernel<<<NODES/4, 256, 0, stream>>>(pos, enc_w1, enc_b1, enc_w2, enc_b2,
                                                msg_w1, h, ai, aj_g);
        pairout_kernel<<<NODES/TI, 512, 0, stream>>>(pos, boxp, msg_w1, msg_b1,
                                                     ai, aj_g, h,
                                                     msg_w2, msg_b2,
                                                     upd_w1, upd_b1, upd_w2, upd_b2,
                                                     dec_w1, dec_b1, dec_w2, dec_b2,
                                                     outp);
    }
}